// Round 9
// baseline (437.079 us; speedup 1.0000x reference)
//
#include <hip/hip_runtime.h>
#include <hip/hip_fp16.h>
#include <math.h>

#define BATCH 2048
#define NBAS 103
#define NPAIR 102     // pair-rows per input feature: (r, r+1), r in [0,101]
#define OUTR 243      // real output width of hidden layers
#define OUTP 256      // padded output width

typedef _Float16 half2v __attribute__((ext_vector_type(2)));

__device__ __forceinline__ float dot2(unsigned a, unsigned b, float c) {
#if __has_builtin(__builtin_amdgcn_fdot2)
    return __builtin_amdgcn_fdot2(__builtin_bit_cast(half2v, a),
                                  __builtin_bit_cast(half2v, b), c, false);
#else
    __half2 ha = __builtin_bit_cast(__half2, a), hb = __builtin_bit_cast(__half2, b);
    c = fmaf(__low2float(ha), __low2float(hb), c);
    c = fmaf(__high2float(ha), __high2float(hb), c);
    return c;
#endif
}

// ---------------- shared spline-eval: (x, i) -> meta {half2 w01, half2 w23, pairoff, flat}
// u = (x+0.56)/0.02. Interval j=floor(u); nonzero basis n=j-3..j clipped to [0,102].
// m.z encodes the table layout pairT[i][ot][r][64]: unit offset (i*408 + idxc) << 6.
// Lane adds (lane>>4)*6528 + (lane&15)*4.
__device__ __forceinline__ uint4 make_meta(float x, int i) {
    float u = (x + 0.56f) * 50.0f;
    bool inr = (u >= 0.0f) && (u < 106.0f);
    float fj = floorf(u);
    float t = u - fj;
    int j = (int)fj;
    j = j < -1 ? -1 : (j > 106 ? 106 : j);
    float omt = 1.0f - t;
    float t2 = t * t, t3 = t2 * t;
    float w[4];
    w[0] = omt * omt * omt * (1.0f / 6.0f);
    w[1] = (3.0f * t3 - 6.0f * t2 + 4.0f) * (1.0f / 6.0f);
    w[2] = (-3.0f * t3 + 3.0f * t2 + 3.0f * t + 1.0f) * (1.0f / 6.0f);
    w[3] = t3 * (1.0f / 6.0f);
    int idx = j - 3;                       // first basis index n
    int idxc = idx < 0 ? 0 : (idx > 99 ? 99 : idx);   // clamp so idxc+3 <= 102
    int d = idx - idxc;                    // nonzero only at edges
    float wc[4];
    #pragma unroll
    for (int m = 0; m < 4; ++m) {          // weight for row idxc+m is w[(idxc+m)-idx]
        int s = m - d;
        wc[m] = (inr && s >= 0 && s < 4) ? w[s] : 0.0f;
    }
    __half2 w01 = __floats2half2_rn(wc[0], wc[1]);
    __half2 w23 = __floats2half2_rn(wc[2], wc[3]);
    uint4 m4;
    m4.x = __builtin_bit_cast(unsigned, w01);
    m4.y = __builtin_bit_cast(unsigned, w23);
    m4.z = (unsigned)((i * (NPAIR * 4) + idxc) << 6);  // layout unit offset
    m4.w = (unsigned)(i * NBAS + idxc);                // flat index for fp32 final layer
    return m4;
}

// ---------------- pair-table build (1-feature, 64-o-tile; best occupancy, R5) ------------
// sw[o][i][n] fp32 -> pairT[i][ot][r][64] packed half2. Block = (feature i, o-tile of 64).
// Phase 1: wave per row, 16 rows/wave, 2 coalesced 256B loads -> tile[64][106]
//          (53-dword stride, gcd(53,32)=1 -> conflict-free both phases).
// Phase 2: 256 threads write 4 full rows of 64 -> 1 KB contiguous per iteration.
// Cross-block streaming: callers map consecutive blockIdx to consecutive i (same ot),
// so in-flight blocks collectively read contiguous sw spans per o.
__device__ __forceinline__ void pairgen_body64(
    const float* __restrict__ sw, int IN, unsigned* __restrict__ pairT,
    __half (*tile)[106], int i, int obase)
{
    int nl = threadIdx.x & 63;
    int w = threadIdx.x >> 6;
    #pragma unroll
    for (int k = 0; k < 16; ++k) {
        int r = w * 16 + k;                // local row 0..63
        int o = obase + r;
        if (o < OUTR) {
            const float* p = sw + ((size_t)o * IN + i) * NBAS;
            tile[r][nl] = __float2half(p[nl]);
            if (nl + 64 < NBAS)
                tile[r][nl + 64] = __float2half(p[nl + 64]);
        } else {
            tile[r][nl] = __ushort_as_half((unsigned short)0);
            if (nl + 64 < 106)
                tile[r][nl + 64] = __ushort_as_half((unsigned short)0);
        }
    }
    __syncthreads();
    int ol = threadIdx.x & 63;             // local o
    int rg = threadIdx.x >> 6;             // row-group 0..3
    unsigned* dst = pairT + (size_t)i * (NPAIR * 4 * 64) + (size_t)(obase >> 6) * (NPAIR * 64);
    for (int r = 0; r < NPAIR; r += 4) {
        int rr = r + rg;
        if (rr < NPAIR) {
            unsigned lo = __half_as_ushort(tile[ol][rr]);
            unsigned hi = __half_as_ushort(tile[ol][rr + 1]);
            dst[(size_t)rr * 64 + ol] = lo | (hi << 16);
        }
    }
}

// standalone pairgen (atomic fallback path): grid (IN, 4); bx=i fastest -> streamed
__global__ __launch_bounds__(256) void pairgen_kernel(
    const float* __restrict__ sw, int IN, unsigned* __restrict__ pairT)
{
    __shared__ __half tile[64][106];       // 13,568 B
    pairgen_body64(sw, IN, pairT, tile, blockIdx.x, blockIdx.y * 64);
}

// ---------------- basis from a plain activation buffer (+ optional fused zeroing; fallback) --
template <int IN>
__global__ __launch_bounds__(256) void basis_kernel(
    const float* __restrict__ xin, int xstride, uint4* __restrict__ meta,
    float4* __restrict__ zbuf)     // if non-null: first 131072 threads zero 2 MB
{
    int e = blockIdx.x * 256 + threadIdx.x;
    if (zbuf && e < (BATCH * OUTP) / 4) zbuf[e] = make_float4(0.f, 0.f, 0.f, 0.f);
    if (e >= BATCH * IN) return;
    int b = e / IN, i = e - b * IN;
    meta[e] = make_meta(xin[(size_t)b * xstride + i], i);
}

// ---------------- FUSED: pairgen[l] (streamed order) + basis_mid[l] ----------------------
// THE R1-STRUCTURE WORKHORSE (best measured total: 400 us with old ls). pg[l] depends
// only on sw[l]; bm[l] only on layer_store[l-1]'s parts -> co-scheduled, complementary
// traffic. The SINGLE SHARED pairT buffer is recycled every layer -- its addresses stay
// L2/L3-resident across the whole net (R8 lesson: 5 separate 25MB tables regressed
// 429 vs 400 despite faster individual kernels).
// grid (1944, 2): y==0 -> pg, 972 active blocks, ot=bx/243, i=bx%243 (i fastest ->
// cross-block streaming reads); y==1 -> bm, e = bx*256+tid covers BATCH*OUTR exactly.
// R7 lesson: do NOT co-dispatch pg with the latency-bound ls (halves its wave slots).
template <bool ADDRES>
__global__ __launch_bounds__(256) void fused_pg_bm_kernel(
    const float* __restrict__ sw, unsigned* __restrict__ pairT,
    const float* __restrict__ hprev, const float* __restrict__ parts,
    uint4* __restrict__ meta, float* __restrict__ hcomb)
{
    if (blockIdx.y == 0) {
        __shared__ __half tile[64][106];
        if (blockIdx.x < 972) {
            int ot = blockIdx.x / 243, i = blockIdx.x - ot * 243;
            pairgen_body64(sw, OUTR, pairT, tile, i, ot * 64);
        }
    } else {
        int e = blockIdx.x * 256 + threadIdx.x;
        if (e >= BATCH * OUTR) return;
        int b = e / OUTR, i = e - b * OUTR;
        size_t addr = (size_t)b * OUTP + i;
        const size_t PS = (size_t)BATCH * OUTP;
        float h = ADDRES ? hprev[addr] : 0.0f;
        #pragma unroll
        for (int s = 0; s < 8; ++s) h += parts[s * PS + addr];
        hcomb[addr] = h;
        meta[e] = make_meta(h, i);
    }
}

// ---------------- FUSED layer-0 front: pairgen(sw0) + basis(x) ----------
// grid (512, 2): y==0 -> pg0, 256 active (i=bx&63 fastest, ot=bx>>6); y==1 -> basis0.
__global__ __launch_bounds__(256) void fused0_kernel(
    const float* __restrict__ sw0, unsigned* __restrict__ pairT,
    const float* __restrict__ xin, uint4* __restrict__ meta)
{
    if (blockIdx.y == 0) {
        __shared__ __half tile[64][106];
        if (blockIdx.x < 256)
            pairgen_body64(sw0, 64, pairT, tile, blockIdx.x & 63, (blockIdx.x >> 6) * 64);
    } else {
        int e = blockIdx.x * 256 + threadIdx.x;   // < 131072 = BATCH*64 exactly
        int b = e >> 6, i = e & 63;
        meta[e] = make_meta(xin[(size_t)b * 64 + i], i);
    }
}

// ---------------- layer gather body: XCD-pinned, 4 batch rows per wave --------------------
// Wave handles FOUR batch rows -> 8 independent 16-B gathers in flight per i-iteration.
// cx = i-slice (XCD id); slice's ~3.2 MB table sub-range lives in that XCD's L2.
// Table layout: lane l gathers at m.z + (l>>4)*6528 + (l&15)*4; rows +2 = +32 uint4.
// NOTE: nt loads tried in R2 -- they demote L2 LRU, doubled FETCH_SIZE, net regression.
template <int IN>
__device__ __forceinline__ void ls_body(
    const unsigned* __restrict__ pairT, const uint4* __restrict__ meta,
    const float* __restrict__ h_in, int hstride,
    const float* __restrict__ bw,
    const float* __restrict__ wbp, const float* __restrict__ wsp,
    float* __restrict__ part, int cx, int by)
{
    const int lane = threadIdx.x & 63;
    const int wave = __builtin_amdgcn_readfirstlane(threadIdx.x >> 6);
    const int b0 = by * 16 + wave * 4;
    const int i0 = (IN * cx) >> 3;
    const int i1 = (IN * (cx + 1)) >> 3;
    const unsigned laneoff = ((unsigned)(lane >> 4) * (NPAIR * 64)) + ((unsigned)(lane & 15) << 2);
    const uint4* mp = meta + (size_t)b0 * IN;
    float a[4][4] = {};
    #pragma unroll 2
    for (int i = i0; i < i1; ++i) {
        uint4 m[4];
        #pragma unroll
        for (int r = 0; r < 4; ++r) m[r] = mp[(size_t)r * IN + i];   // wave-uniform -> s_load
        uint4 lo[4], hi[4];
        #pragma unroll
        for (int r = 0; r < 4; ++r) {
            const uint4* p = (const uint4*)(pairT + m[r].z + laneoff);
            lo[r] = p[0];                  // pair rows (r0, r0+1), 4 o's
            hi[r] = p[32];                 // pair rows (r0+2, r0+3)
        }
        #pragma unroll
        for (int r = 0; r < 4; ++r) {
            a[r][0] = dot2(m[r].x, lo[r].x, a[r][0]);
            a[r][1] = dot2(m[r].x, lo[r].y, a[r][1]);
            a[r][2] = dot2(m[r].x, lo[r].z, a[r][2]);
            a[r][3] = dot2(m[r].x, lo[r].w, a[r][3]);
            a[r][0] = dot2(m[r].y, hi[r].x, a[r][0]);
            a[r][1] = dot2(m[r].y, hi[r].y, a[r][1]);
            a[r][2] = dot2(m[r].y, hi[r].z, a[r][2]);
            a[r][3] = dot2(m[r].y, hi[r].w, a[r][3]);
        }
    }
    float wsv = wsp[0];
    float wbv = wbp[0];
    #pragma unroll
    for (int r = 0; r < 4; ++r) {
        float4 v = make_float4(wsv * a[r][0], wsv * a[r][1], wsv * a[r][2], wsv * a[r][3]);
        if (wbv != 0.0f) {                 // base path: never taken for given inputs (wb==0)
            float* pv = &v.x;
            for (int c = 0; c < 4; ++c) {
                int o = lane * 4 + c;
                if (o < OUTR) {
                    float bs = 0.0f;
                    for (int i = i0; i < i1; ++i) {
                        float xx = h_in[(size_t)(b0 + r) * hstride + i];
                        bs = fmaf(xx / (1.0f + expf(-xx)), bw[o * IN + i], bs);
                    }
                    pv[c] += wbv * bs;
                }
            }
        }
        float* d = part + ((size_t)cx * BATCH + b0 + r) * OUTP + lane * 4;
        *(float4*)d = v;
    }
}

// standalone layer kernel: grid (8, BATCH/16)
template <int IN>
__global__ __launch_bounds__(256, 4) void layer_store_kernel(
    const unsigned* __restrict__ pairT, const uint4* __restrict__ meta,
    const float* __restrict__ h_in, int hstride,
    const float* __restrict__ bw,
    const float* __restrict__ wbp, const float* __restrict__ wsp,
    float* __restrict__ part)
{
    ls_body<IN>(pairT, meta, h_in, hstride, bw, wbp, wsp, part, blockIdx.x, blockIdx.y);
}

// ---------------- FALLBACK layer kernel (atomic version, needs only 37.5 MB ws) ----------
template <int IN, bool RES>
__global__ __launch_bounds__(256, 8) void layer_atomic_kernel(
    const unsigned* __restrict__ pairT, const uint4* __restrict__ meta,
    const float* __restrict__ h_in, int hstride,
    const float* __restrict__ bw,
    const float* __restrict__ wbp, const float* __restrict__ wsp,
    float* __restrict__ out)
{
    const int lane = threadIdx.x & 63;
    const int wave = __builtin_amdgcn_readfirstlane(threadIdx.x >> 6);
    const int b = blockIdx.y * 4 + wave;
    const int cx = blockIdx.x;
    const int i0 = (IN * cx) >> 3;
    const int i1 = (IN * (cx + 1)) >> 3;
    const unsigned laneoff = ((unsigned)(lane >> 4) * (NPAIR * 64)) + ((unsigned)(lane & 15) << 2);
    const uint4* mp = meta + (size_t)b * IN;
    float acc[4] = {0.f, 0.f, 0.f, 0.f};
    #pragma unroll 2
    for (int i = i0; i < i1; ++i) {
        uint4 m = mp[i];
        const uint4* pA = (const uint4*)(pairT + m.z + laneoff);
        uint4 ra = pA[0];
        uint4 rb = pA[32];
        acc[0] = dot2(m.x, ra.x, acc[0]); acc[1] = dot2(m.x, ra.y, acc[1]);
        acc[2] = dot2(m.x, ra.z, acc[2]); acc[3] = dot2(m.x, ra.w, acc[3]);
        acc[0] = dot2(m.y, rb.x, acc[0]); acc[1] = dot2(m.y, rb.y, acc[1]);
        acc[2] = dot2(m.y, rb.z, acc[2]); acc[3] = dot2(m.y, rb.w, acc[3]);
    }
    float wsv = wsp[0];
    float wbv = wbp[0];
    #pragma unroll
    for (int c = 0; c < 4; ++c) {
        int o = lane * 4 + c;
        float v = wsv * acc[c];
        if (RES && cx == 0) v += h_in[(size_t)b * hstride + o];
        if (wbv != 0.0f && o < OUTR) {
            float bs = 0.0f;
            for (int i = i0; i < i1; ++i) {
                float xx = h_in[(size_t)b * hstride + i];
                bs = fmaf(xx / (1.0f + expf(-xx)), bw[o * IN + i], bs);
            }
            v += wbv * bs;
        }
        unsafeAtomicAdd(&out[(size_t)b * OUTP + o], v);
    }
}

// ---------------- FUSED tail: h5 = h4 + sum(parts) computed inline + final 243 -> 1 --------
__global__ __launch_bounds__(256) void final_fused_kernel(
    const float* __restrict__ sw5,          // (243*103,) original fp32 layout
    const float* __restrict__ hprev,        // h4, stride OUTP
    const float* __restrict__ parts,        // 8 buffers of BATCH*OUTP floats
    const float* __restrict__ bw5,
    const float* __restrict__ wbp, const float* __restrict__ wsp,
    float* __restrict__ out)
{
    int wave = threadIdx.x >> 6, lane = threadIdx.x & 63;
    int b = blockIdx.x * 4 + wave;
    const size_t PS = (size_t)BATCH * OUTP;
    float s = 0.0f, bs = 0.0f;
    for (int i = lane; i < OUTR; i += 64) {
        size_t addr = (size_t)b * OUTP + i;
        float h = hprev[addr];
        #pragma unroll
        for (int ss = 0; ss < 8; ++ss) h += parts[ss * PS + addr];
        uint4 m = make_meta(h, i);
        __half2 w01 = __builtin_bit_cast(__half2, m.x);
        __half2 w23 = __builtin_bit_cast(__half2, m.y);
        const float* p = sw5 + m.w;
        s += __low2float(w01) * p[0] + __high2float(w01) * p[1]
           + __low2float(w23) * p[2] + __high2float(w23) * p[3];
        bs = fmaf(h / (1.0f + expf(-h)), bw5[i], bs);   // base path partial (wb==0 typ.)
    }
    #pragma unroll
    for (int d = 32; d; d >>= 1) {
        s += __shfl_down(s, d, 64);
        bs += __shfl_down(bs, d, 64);
    }
    if (lane == 0) out[b] = wsp[0] * s + wbp[0] * bs;
}

// ---------------- final layer 243 -> 1 (atomic fallback path) ----------------
__global__ __launch_bounds__(256) void final_kernel(
    const float* __restrict__ sw5,
    const uint4* __restrict__ meta,
    const float* __restrict__ h, const float* __restrict__ bw5,
    const float* __restrict__ wbp, const float* __restrict__ wsp,
    float* __restrict__ out)
{
    int wave = threadIdx.x >> 6, lane = threadIdx.x & 63;
    int b = blockIdx.x * 4 + wave;
    float s = 0.0f;
    for (int i = lane; i < OUTR; i += 64) {
        uint4 m = meta[(size_t)b * OUTR + i];
        __half2 w01 = __builtin_bit_cast(__half2, m.x);
        __half2 w23 = __builtin_bit_cast(__half2, m.y);
        const float* p = sw5 + m.w;
        s += __low2float(w01) * p[0] + __high2float(w01) * p[1]
           + __low2float(w23) * p[2] + __high2float(w23) * p[3];
    }
    #pragma unroll
    for (int d = 32; d; d >>= 1) s += __shfl_down(s, d, 64);
    if (lane == 0) {
        float v = wsp[0] * s;
        float wbv = wbp[0];
        if (wbv != 0.0f) {
            float bs = 0.0f;
            for (int i = 0; i < OUTR; ++i) {
                float xx = h[(size_t)b * OUTP + i];
                bs = fmaf(xx / (1.0f + expf(-xx)), bw5[i], bs);
            }
            v += wbv * bs;
        }
        out[b] = v;
    }
}

extern "C" void kernel_launch(void* const* d_in, const int* in_sizes, int n_in,
                              void* d_out, int out_size, void* d_ws, size_t ws_size,
                              hipStream_t stream)
{
    const float* x = (const float*)d_in[0];
    const float *bw[6], *sw[6], *wb[6], *ws[6];
    for (int l = 0; l < 6; ++l) {
        bw[l] = (const float*)d_in[1 + 4 * l];
        sw[l] = (const float*)d_in[2 + 4 * l];
        wb[l] = (const float*)d_in[3 + 4 * l];
        ws[l] = (const float*)d_in[4 + 4 * l];
    }
    char* base = (char*)d_ws;
    float* outp = (float*)d_out;
    const int NB243 = (BATCH * OUTR + 255) / 256;

    const size_t NEED_MID = 54315008;        // primary path (R1 structure + new gather)
    const size_t NEED_ATM = 37537792;        // atomic fallback

    if (ws_size >= NEED_MID) {
        // ---- primary workspace map (single shared table, recycled -> L2/L3-warm) ----
        // pairT1 :          0 .. 25,380,864   (243*408*64*4)
        // meta   : 25,380,864 .. 33,343,488   (2048*243*16)
        // parts  : 33,343,488 .. 50,120,704   (8 * 2 MB)
        // hcA    : 50,120,704 .. 52,217,856
        // hcB    : 52,217,856 .. 54,315,008
        unsigned* pairT1 = (unsigned*)(base + 0);
        uint4*    meta   = (uint4*)(base + 25380864);
        float*    parts  = (float*)(base + 33343488);
        float*    hcA    = (float*)(base + 50120704);
        float*    hcB    = (float*)(base + 52217856);

        fused0_kernel<<<dim3(512, 2), 256, 0, stream>>>(sw[0], pairT1, x, meta);
        layer_store_kernel<64><<<dim3(8, BATCH / 16), 256, 0, stream>>>(
            pairT1, meta, x, 64, bw[0], wb[0], ws[0], parts);

        float* hin = hcA; float* hout = hcB;   // hin = h_l carrier
        for (int l = 1; l <= 4; ++l) {
            if (l == 1)
                fused_pg_bm_kernel<false><<<dim3(1944, 2), 256, 0, stream>>>(
                    sw[l], pairT1, nullptr, parts, meta, hin);
            else
                fused_pg_bm_kernel<true><<<dim3(1944, 2), 256, 0, stream>>>(
                    sw[l], pairT1, hout, parts, meta, hin);
            layer_store_kernel<243><<<dim3(8, BATCH / 16), 256, 0, stream>>>(
                pairT1, meta, hin, OUTP, bw[l], wb[l], ws[l], parts);
            float* tmp = hin; hin = hout; hout = tmp;   // hout now holds h_l
        }
        // fused tail: h5 = h4 + sum(parts of layer 4) inline; h4 is in hout
        final_fused_kernel<<<BATCH / 4, 256, 0, stream>>>(
            sw[5], hout, parts, bw[5], wb[5], ws[5], outp);
    } else {
        // ---- fallback: proven atomic path, needs 37,537,792 B ----
        if (ws_size < NEED_ATM) return;
        unsigned* pairT1 = (unsigned*)(base + 0);
        uint4*    meta   = (uint4*)(base + 25380864);
        float* hA = (float*)(base + 33343488);
        float* hB = (float*)(base + 35440640);
        pairgen_kernel<<<dim3(64, 4), 256, 0, stream>>>(sw[0], 64, pairT1);
        basis_kernel<64><<<(BATCH * 64) / 256, 256, 0, stream>>>(x, 64, meta, (float4*)hA);
        layer_atomic_kernel<64, false><<<dim3(8, BATCH / 4), 256, 0, stream>>>(
            pairT1, meta, x, 64, bw[0], wb[0], ws[0], hA);
        float* hin = hA; float* hout = hB;
        for (int l = 1; l <= 4; ++l) {
            pairgen_kernel<<<dim3(OUTR, 4), 256, 0, stream>>>(sw[l], OUTR, pairT1);
            basis_kernel<243><<<NB243, 256, 0, stream>>>(hin, OUTP, meta, (float4*)hout);
            layer_atomic_kernel<243, true><<<dim3(8, BATCH / 4), 256, 0, stream>>>(
                pairT1, meta, hin, OUTP, bw[l], wb[l], ws[l], hout);
            float* tmp = hin; hin = hout; hout = tmp;
        }
        basis_kernel<243><<<NB243, 256, 0, stream>>>(hin, OUTP, meta, nullptr);
        final_kernel<<<BATCH / 4, 256, 0, stream>>>(sw[5], meta, hin, bw[5], wb[5], ws[5], outp);
    }
}

// Round 10
// 397.424 us; speedup vs baseline: 1.0998x; 1.0998x over previous
//
#include <hip/hip_runtime.h>
#include <hip/hip_fp16.h>
#include <math.h>

#define BATCH 2048
#define NBAS 103
#define NPAIR 102     // pair-rows per input feature: (r, r+1), r in [0,101]
#define OUTR 243      // real output width of hidden layers
#define OUTP 256      // padded output width

typedef _Float16 half2v __attribute__((ext_vector_type(2)));

__device__ __forceinline__ float dot2(unsigned a, unsigned b, float c) {
#if __has_builtin(__builtin_amdgcn_fdot2)
    return __builtin_amdgcn_fdot2(__builtin_bit_cast(half2v, a),
                                  __builtin_bit_cast(half2v, b), c, false);
#else
    __half2 ha = __builtin_bit_cast(__half2, a), hb = __builtin_bit_cast(__half2, b);
    c = fmaf(__low2float(ha), __low2float(hb), c);
    c = fmaf(__high2float(ha), __high2float(hb), c);
    return c;
#endif
}

// ---------------- shared spline-eval: (x, i) -> meta {half2 w01, half2 w23, pairoff, flat}
// u = (x+0.56)/0.02. Interval j=floor(u); nonzero basis n=j-3..j clipped to [0,102].
// m.z = (i*NPAIR + idxc) << 8 : pair-row offset in the R1 table layout pairT[i][r][256].
__device__ __forceinline__ uint4 make_meta(float x, int i) {
    float u = (x + 0.56f) * 50.0f;
    bool inr = (u >= 0.0f) && (u < 106.0f);
    float fj = floorf(u);
    float t = u - fj;
    int j = (int)fj;
    j = j < -1 ? -1 : (j > 106 ? 106 : j);
    float omt = 1.0f - t;
    float t2 = t * t, t3 = t2 * t;
    float w[4];
    w[0] = omt * omt * omt * (1.0f / 6.0f);
    w[1] = (3.0f * t3 - 6.0f * t2 + 4.0f) * (1.0f / 6.0f);
    w[2] = (-3.0f * t3 + 3.0f * t2 + 3.0f * t + 1.0f) * (1.0f / 6.0f);
    w[3] = t3 * (1.0f / 6.0f);
    int idx = j - 3;                       // first basis index n
    int idxc = idx < 0 ? 0 : (idx > 99 ? 99 : idx);   // clamp so idxc+3 <= 102
    int d = idx - idxc;                    // nonzero only at edges
    float wc[4];
    #pragma unroll
    for (int m = 0; m < 4; ++m) {          // weight for row idxc+m is w[(idxc+m)-idx]
        int s = m - d;
        wc[m] = (inr && s >= 0 && s < 4) ? w[s] : 0.0f;
    }
    __half2 w01 = __floats2half2_rn(wc[0], wc[1]);
    __half2 w23 = __floats2half2_rn(wc[2], wc[3]);
    uint4 m4;
    m4.x = __builtin_bit_cast(unsigned, w01);
    m4.y = __builtin_bit_cast(unsigned, w23);
    m4.z = (unsigned)((i * NPAIR + idxc) << 8);   // pair-row offset in half2/uint units
    m4.w = (unsigned)(i * NBAS + idxc);           // flat index for fp32 final layer
    return m4;
}

// ---------------- pair-table build: sw[o][i][n] (fp32) -> pairT[i][r][o] = half2(v_r,v_r+1)
// R1-EXACT 32-row-tile body (measured best total: 400 us). Block = (feature i, 32-o-tile).
// Phase 1: each wave loads 8 rows (16 independent coalesced 256B loads) into
// tile[32][106] (53-dword stride, gcd(53,32)=1 -> conflict-free column reads).
// Phase 2: packed half2 writes, 128B contiguous per 32-lane group.
// R5/R9 lesson: the 64-row/contiguous-write variant is SLOWER (88 vs 81 us standalone;
// fewer blocks + more latency exposure per block). Keep 32-row.
__device__ __forceinline__ void pairgen_body(
    const float* __restrict__ sw, int IN, unsigned* __restrict__ pairT,
    __half (*tile)[106], int i, int obase)
{
    int nl = threadIdx.x & 63;
    int w = threadIdx.x >> 6;
    #pragma unroll
    for (int k = 0; k < 8; ++k) {
        int r = w * 8 + k;                 // local row 0..31
        int o = obase + r;
        if (o < OUTR) {
            const float* p = sw + ((size_t)o * IN + i) * NBAS;
            tile[r][nl] = __float2half(p[nl]);                        // n = 0..63
            if (nl + 64 < NBAS)                                        // n = 64..102 ONLY
                tile[r][nl + 64] = __float2half(p[nl + 64]);
        }
    }
    __syncthreads();
    unsigned* dst = pairT + (size_t)i * NPAIR * 256 + obase;
    for (int idx = threadIdx.x; idx < NPAIR * 32; idx += 256) {
        int p = idx >> 5, o = idx & 31;    // pair-row, local o
        unsigned v = 0;
        if (obase + o < OUTR) {
            unsigned lo = __half_as_ushort(tile[o][p]);
            unsigned hi = __half_as_ushort(tile[o][p + 1]);
            v = lo | (hi << 16);
        }
        dst[(size_t)p * 256 + o] = v;
    }
}

// standalone pairgen (atomic fallback path): grid (IN, 8)
__global__ __launch_bounds__(256) void pairgen_kernel(
    const float* __restrict__ sw, int IN, unsigned* __restrict__ pairT)
{
    __shared__ __half tile[32][106];       // 6,784 B
    pairgen_body(sw, IN, pairT, tile, blockIdx.x, blockIdx.y * 32);
}

// ---------------- basis from a plain activation buffer (+ optional fused zeroing; fallback) --
template <int IN>
__global__ __launch_bounds__(256) void basis_kernel(
    const float* __restrict__ xin, int xstride, uint4* __restrict__ meta,
    float4* __restrict__ zbuf)     // if non-null: first 131072 threads zero 2 MB
{
    int e = blockIdx.x * 256 + threadIdx.x;
    if (zbuf && e < (BATCH * OUTP) / 4) zbuf[e] = make_float4(0.f, 0.f, 0.f, 0.f);
    if (e >= BATCH * IN) return;
    int b = e / IN, i = e - b * IN;
    meta[e] = make_meta(xin[(size_t)b * xstride + i], i);
}

// ---------------- FUSED: pairgen[l] + basis_mid[l] (R1-exact workhorse) -------------------
// pg[l] depends only on sw[l]; bm[l] only on layer_store[l-1]'s parts -> co-scheduled.
// Single shared pairT recycled every layer (addresses stay L2/L3-warm; R8's 5 separate
// tables regressed 429 vs 400). grid (1944, 2): y==0 -> pg (i=bx>>3, ot=bx&7, all
// active); y==1 -> bm (e = bx*256+tid covers BATCH*OUTR exactly).
template <bool ADDRES>
__global__ __launch_bounds__(256) void fused_pg_bm_kernel(
    const float* __restrict__ sw, unsigned* __restrict__ pairT,
    const float* __restrict__ hprev, const float* __restrict__ parts,
    uint4* __restrict__ meta, float* __restrict__ hcomb)
{
    if (blockIdx.y == 0) {
        __shared__ __half tile[32][106];
        pairgen_body(sw, OUTR, pairT, tile, blockIdx.x >> 3, (blockIdx.x & 7) * 32);
    } else {
        int e = blockIdx.x * 256 + threadIdx.x;
        if (e >= BATCH * OUTR) return;
        int b = e / OUTR, i = e - b * OUTR;
        size_t addr = (size_t)b * OUTP + i;
        const size_t PS = (size_t)BATCH * OUTP;
        float h = ADDRES ? hprev[addr] : 0.0f;
        #pragma unroll
        for (int s = 0; s < 8; ++s) h += parts[s * PS + addr];
        hcomb[addr] = h;
        meta[e] = make_meta(h, i);
    }
}

// ---------------- FUSED layer-0 front: pairgen(sw0) (y==0) + basis(x) (y==1) ---------------
// grid (512, 2): y==0 -> i = x>>3 (0..63), otile = x&7; y==1 -> e = x*256+tid (= BATCH*64).
__global__ __launch_bounds__(256) void fused0_kernel(
    const float* __restrict__ sw0, unsigned* __restrict__ pairT,
    const float* __restrict__ xin, uint4* __restrict__ meta)
{
    if (blockIdx.y == 0) {
        __shared__ __half tile[32][106];
        pairgen_body(sw0, 64, pairT, tile, blockIdx.x >> 3, (blockIdx.x & 7) * 32);
    } else {
        int e = blockIdx.x * 256 + threadIdx.x;   // < 131072 = BATCH*64 exactly
        int b = e >> 6, i = e & 63;
        meta[e] = make_meta(xin[(size_t)b * 64 + i], i);
    }
}

// ---------------- layer kernel: R1-exact XCD-pinned gather, 2 batch rows per wave ---------
// Block = 256 threads (4 waves); wave handles TWO batch rows, lane covers o = lane*4..+3.
// grid = (8, BATCH/8): blockIdx.x = i-slice (8-way). Linear block id % 8 == slice ->
// slice pinned to one XCD whose L2 holds its ~3.2 MB of pairT. Slice cx stores to its own
// partial buffer -- no atomics, no zero-init, full-line stores.
// wave is readfirstlane-uniform -> meta loads compile to s_load via K$ (the R0->R1 ls win).
// R9 lesson: 4-row/wave + new layout was NOT an isolated win; this 2-row config is the
// measured-best. NOTE: nt loads (R2) demote L2 LRU -- net regression; don't.
template <int IN>
__global__ __launch_bounds__(256, 8) void layer_store_kernel(
    const unsigned* __restrict__ pairT, const uint4* __restrict__ meta,
    const float* __restrict__ h_in, int hstride,
    const float* __restrict__ bw,
    const float* __restrict__ wbp, const float* __restrict__ wsp,
    float* __restrict__ part)
{
    const int lane = threadIdx.x & 63;
    const int wave = __builtin_amdgcn_readfirstlane(threadIdx.x >> 6);
    const int b0 = blockIdx.y * 8 + wave * 2;
    const int cx = blockIdx.x;             // i-slice = XCD id
    const int i0 = (IN * cx) >> 3;
    const int i1 = (IN * (cx + 1)) >> 3;
    const uint4* mp0 = meta + (size_t)b0 * IN;
    const uint4* mp1 = mp0 + IN;
    float a0[4] = {0.f, 0.f, 0.f, 0.f};
    float a1[4] = {0.f, 0.f, 0.f, 0.f};
    #pragma unroll 2
    for (int i = i0; i < i1; ++i) {
        uint4 m0 = mp0[i];                             // wave-uniform -> s_load
        uint4 m1 = mp1[i];
        const uint4* pA = (const uint4*)(pairT + m0.z) + lane;
        const uint4* pB = (const uint4*)(pairT + m1.z) + lane;
        uint4 ra = pA[0];                              // b0: pair (r0, r0+1)
        uint4 rb = pA[128];                            // b0: pair (r0+2, r0+3)
        uint4 rc = pB[0];                              // b0+1 likewise
        uint4 rd = pB[128];
        a0[0] = dot2(m0.x, ra.x, a0[0]); a0[1] = dot2(m0.x, ra.y, a0[1]);
        a0[2] = dot2(m0.x, ra.z, a0[2]); a0[3] = dot2(m0.x, ra.w, a0[3]);
        a0[0] = dot2(m0.y, rb.x, a0[0]); a0[1] = dot2(m0.y, rb.y, a0[1]);
        a0[2] = dot2(m0.y, rb.z, a0[2]); a0[3] = dot2(m0.y, rb.w, a0[3]);
        a1[0] = dot2(m1.x, rc.x, a1[0]); a1[1] = dot2(m1.x, rc.y, a1[1]);
        a1[2] = dot2(m1.x, rc.z, a1[2]); a1[3] = dot2(m1.x, rc.w, a1[3]);
        a1[0] = dot2(m1.y, rd.x, a1[0]); a1[1] = dot2(m1.y, rd.y, a1[1]);
        a1[2] = dot2(m1.y, rd.z, a1[2]); a1[3] = dot2(m1.y, rd.w, a1[3]);
    }
    float wsv = wsp[0];
    float wbv = wbp[0];
    float4 v0 = make_float4(wsv * a0[0], wsv * a0[1], wsv * a0[2], wsv * a0[3]);
    float4 v1 = make_float4(wsv * a1[0], wsv * a1[1], wsv * a1[2], wsv * a1[3]);
    if (wbv != 0.0f) {                     // base path: never taken for given inputs (wb==0)
        float* pv0 = &v0.x; float* pv1 = &v1.x;
        for (int c = 0; c < 4; ++c) {
            int o = lane * 4 + c;
            if (o < OUTR) {
                float bs0 = 0.0f, bs1 = 0.0f;
                for (int i = i0; i < i1; ++i) {
                    float x0 = h_in[(size_t)b0 * hstride + i];
                    float x1 = h_in[(size_t)(b0 + 1) * hstride + i];
                    bs0 = fmaf(x0 / (1.0f + expf(-x0)), bw[o * IN + i], bs0);
                    bs1 = fmaf(x1 / (1.0f + expf(-x1)), bw[o * IN + i], bs1);
                }
                pv0[c] += wbv * bs0;
                pv1[c] += wbv * bs1;
            }
        }
    }
    float* d0 = part + ((size_t)cx * BATCH + b0) * OUTP + lane * 4;
    *(float4*)d0 = v0;
    *(float4*)(d0 + OUTP) = v1;
}

// ---------------- FALLBACK layer kernel (atomic version, needs only 37.5 MB ws) ----------
template <int IN, bool RES>
__global__ __launch_bounds__(256, 8) void layer_atomic_kernel(
    const unsigned* __restrict__ pairT, const uint4* __restrict__ meta,
    const float* __restrict__ h_in, int hstride,
    const float* __restrict__ bw,
    const float* __restrict__ wbp, const float* __restrict__ wsp,
    float* __restrict__ out)
{
    const int lane = threadIdx.x & 63;
    const int wave = __builtin_amdgcn_readfirstlane(threadIdx.x >> 6);
    const int b = blockIdx.y * 4 + wave;
    const int cx = blockIdx.x;
    const int i0 = (IN * cx) >> 3;
    const int i1 = (IN * (cx + 1)) >> 3;
    const uint4* mp = meta + (size_t)b * IN;
    float acc[4] = {0.f, 0.f, 0.f, 0.f};
    #pragma unroll 2
    for (int i = i0; i < i1; ++i) {
        uint4 m = mp[i];
        const uint4* pA = (const uint4*)(pairT + m.z) + lane;
        uint4 ra = pA[0];
        uint4 rb = pA[128];
        acc[0] = dot2(m.x, ra.x, acc[0]); acc[1] = dot2(m.x, ra.y, acc[1]);
        acc[2] = dot2(m.x, ra.z, acc[2]); acc[3] = dot2(m.x, ra.w, acc[3]);
        acc[0] = dot2(m.y, rb.x, acc[0]); acc[1] = dot2(m.y, rb.y, acc[1]);
        acc[2] = dot2(m.y, rb.z, acc[2]); acc[3] = dot2(m.y, rb.w, acc[3]);
    }
    float wsv = wsp[0];
    float wbv = wbp[0];
    #pragma unroll
    for (int c = 0; c < 4; ++c) {
        int o = lane * 4 + c;
        float v = wsv * acc[c];
        if (RES && cx == 0) v += h_in[(size_t)b * hstride + o];
        if (wbv != 0.0f && o < OUTR) {
            float bs = 0.0f;
            for (int i = i0; i < i1; ++i) {
                float xx = h_in[(size_t)b * hstride + i];
                bs = fmaf(xx / (1.0f + expf(-xx)), bw[o * IN + i], bs);
            }
            v += wbv * bs;
        }
        unsafeAtomicAdd(&out[(size_t)b * OUTP + o], v);
    }
}

// ---------------- FUSED tail: h5 = h4 + sum(parts) inline + final 243 -> 1 ----------------
// Replaces basis_mid<true> + final_kernel: no 16 MB meta round-trip, no hcomb write,
// one dispatch fewer. Wave per batch row; lane strides i; 9-stream coalesced loads.
__global__ __launch_bounds__(256) void final_fused_kernel(
    const float* __restrict__ sw5,          // (243*103,) original fp32 layout
    const float* __restrict__ hprev,        // h4, stride OUTP
    const float* __restrict__ parts,        // 8 buffers of BATCH*OUTP floats
    const float* __restrict__ bw5,
    const float* __restrict__ wbp, const float* __restrict__ wsp,
    float* __restrict__ out)
{
    int wave = threadIdx.x >> 6, lane = threadIdx.x & 63;
    int b = blockIdx.x * 4 + wave;
    const size_t PS = (size_t)BATCH * OUTP;
    float s = 0.0f, bs = 0.0f;
    for (int i = lane; i < OUTR; i += 64) {
        size_t addr = (size_t)b * OUTP + i;
        float h = hprev[addr];
        #pragma unroll
        for (int ss = 0; ss < 8; ++ss) h += parts[ss * PS + addr];
        uint4 m = make_meta(h, i);
        __half2 w01 = __builtin_bit_cast(__half2, m.x);
        __half2 w23 = __builtin_bit_cast(__half2, m.y);
        const float* p = sw5 + m.w;
        s += __low2float(w01) * p[0] + __high2float(w01) * p[1]
           + __low2float(w23) * p[2] + __high2float(w23) * p[3];
        bs = fmaf(h / (1.0f + expf(-h)), bw5[i], bs);   // base path partial (wb==0 typ.)
    }
    #pragma unroll
    for (int d = 32; d; d >>= 1) {
        s += __shfl_down(s, d, 64);
        bs += __shfl_down(bs, d, 64);
    }
    if (lane == 0) out[b] = wsp[0] * s + wbp[0] * bs;
}

// ---------------- final layer 243 -> 1 (atomic fallback path) ----------------
__global__ __launch_bounds__(256) void final_kernel(
    const float* __restrict__ sw5,
    const uint4* __restrict__ meta,
    const float* __restrict__ h, const float* __restrict__ bw5,
    const float* __restrict__ wbp, const float* __restrict__ wsp,
    float* __restrict__ out)
{
    int wave = threadIdx.x >> 6, lane = threadIdx.x & 63;
    int b = blockIdx.x * 4 + wave;
    float s = 0.0f;
    for (int i = lane; i < OUTR; i += 64) {
        uint4 m = meta[(size_t)b * OUTR + i];
        __half2 w01 = __builtin_bit_cast(__half2, m.x);
        __half2 w23 = __builtin_bit_cast(__half2, m.y);
        const float* p = sw5 + m.w;
        s += __low2float(w01) * p[0] + __high2float(w01) * p[1]
           + __low2float(w23) * p[2] + __high2float(w23) * p[3];
    }
    #pragma unroll
    for (int d = 32; d; d >>= 1) s += __shfl_down(s, d, 64);
    if (lane == 0) {
        float v = wsp[0] * s;
        float wbv = wbp[0];
        if (wbv != 0.0f) {
            float bs = 0.0f;
            for (int i = 0; i < OUTR; ++i) {
                float xx = h[(size_t)b * OUTP + i];
                bs = fmaf(xx / (1.0f + expf(-xx)), bw5[i], bs);
            }
            v += wbv * bs;
        }
        out[b] = v;
    }
}

extern "C" void kernel_launch(void* const* d_in, const int* in_sizes, int n_in,
                              void* d_out, int out_size, void* d_ws, size_t ws_size,
                              hipStream_t stream)
{
    const float* x = (const float*)d_in[0];
    const float *bw[6], *sw[6], *wb[6], *ws[6];
    for (int l = 0; l < 6; ++l) {
        bw[l] = (const float*)d_in[1 + 4 * l];
        sw[l] = (const float*)d_in[2 + 4 * l];
        wb[l] = (const float*)d_in[3 + 4 * l];
        ws[l] = (const float*)d_in[4 + 4 * l];
    }
    char* base = (char*)d_ws;
    float* outp = (float*)d_out;
    const int NB243 = (BATCH * OUTR + 255) / 256;

    const size_t NEED_MID = 54315008;        // primary path (R1 structure)
    const size_t NEED_ATM = 37537792;        // atomic fallback

    if (ws_size >= NEED_MID) {
        // ---- primary workspace map (R1: single shared table, recycled -> L2/L3-warm) ----
        // pairT1 :          0 .. 25,380,864   (243*102*256*4)
        // meta   : 25,380,864 .. 33,343,488   (2048*243*16)
        // parts  : 33,343,488 .. 50,120,704   (8 * 2 MB)
        // hcA    : 50,120,704 .. 52,217,856
        // hcB    : 52,217,856 .. 54,315,008
        unsigned* pairT1 = (unsigned*)(base + 0);
        uint4*    meta   = (uint4*)(base + 25380864);
        float*    parts  = (float*)(base + 33343488);
        float*    hcA    = (float*)(base + 50120704);
        float*    hcB    = (float*)(base + 52217856);

        fused0_kernel<<<dim3(512, 2), 256, 0, stream>>>(sw[0], pairT1, x, meta);
        layer_store_kernel<64><<<dim3(8, BATCH / 8), 256, 0, stream>>>(
            pairT1, meta, x, 64, bw[0], wb[0], ws[0], parts);

        float* hin = hcA; float* hout = hcB;   // hin = h_l carrier
        for (int l = 1; l <= 4; ++l) {
            if (l == 1)
                fused_pg_bm_kernel<false><<<dim3(1944, 2), 256, 0, stream>>>(
                    sw[l], pairT1, nullptr, parts, meta, hin);
            else
                fused_pg_bm_kernel<true><<<dim3(1944, 2), 256, 0, stream>>>(
                    sw[l], pairT1, hout, parts, meta, hin);
            layer_store_kernel<243><<<dim3(8, BATCH / 8), 256, 0, stream>>>(
                pairT1, meta, hin, OUTP, bw[l], wb[l], ws[l], parts);
            float* tmp = hin; hin = hout; hout = tmp;   // hout now holds h_l
        }
        // fused tail: h5 = h4 + sum(parts of layer 4) inline; h4 is in hout
        final_fused_kernel<<<BATCH / 4, 256, 0, stream>>>(
            sw[5], hout, parts, bw[5], wb[5], ws[5], outp);
    } else {
        // ---- fallback: proven atomic path, needs 37,537,792 B ----
        if (ws_size < NEED_ATM) return;
        unsigned* pairT1 = (unsigned*)(base + 0);
        uint4*    meta   = (uint4*)(base + 25380864);
        float* hA = (float*)(base + 33343488);
        float* hB = (float*)(base + 35440640);
        pairgen_kernel<<<dim3(64, 8), 256, 0, stream>>>(sw[0], 64, pairT1);
        basis_kernel<64><<<(BATCH * 64) / 256, 256, 0, stream>>>(x, 64, meta, (float4*)hA);
        layer_atomic_kernel<64, false><<<dim3(8, BATCH / 4), 256, 0, stream>>>(
            pairT1, meta, x, 64, bw[0], wb[0], ws[0], hA);
        float* hin = hA; float* hout = hB;
        for (int l = 1; l <= 4; ++l) {
            pairgen_kernel<<<dim3(OUTR, 8), 256, 0, stream>>>(sw[l], OUTR, pairT1);
            basis_kernel<243><<<NB243, 256, 0, stream>>>(hin, OUTP, meta, (float4*)hout);
            layer_atomic_kernel<243, true><<<dim3(8, BATCH / 4), 256, 0, stream>>>(
                pairT1, meta, hin, OUTP, bw[l], wb[l], ws[l], hout);
            float* tmp = hin; hin = hout; hout = tmp;
        }
        basis_kernel<243><<<NB243, 256, 0, stream>>>(hin, OUTP, meta, nullptr);
        final_kernel<<<BATCH / 4, 256, 0, stream>>>(sw[5], meta, hin, bw[5], wb[5], ws[5], outp);
    }
}